// Round 12
// baseline (393.089 us; speedup 1.0000x reference)
//
#include <hip/hip_runtime.h>

#define HIDDEN 2048
#define NB 64
#define NT 512
#define NK 49

#define BM 128          // rows per block (4 waves x 32)
#define BK 64           // k-floats per chunk
#define NCH (HIDDEN/BK) // 32 chunks

typedef __attribute__((ext_vector_type(4))) float f32x4;
typedef __attribute__((ext_vector_type(8))) short short8;

__device__ __forceinline__ unsigned cvtpk_bf16(float a, float b) {
    unsigned r;
    asm("v_cvt_pk_bf16_f32 %0, %1, %2" : "=v"(r) : "v"(a), "v"(b));
    return r;
}

// scalar RNE f32->bf16 (convert kernel only; not perf-critical)
__device__ __forceinline__ unsigned short f2bf(float x) {
    union { float f; unsigned u; } v; v.f = x;
    unsigned r = v.u + 0x7FFF + ((v.u >> 16) & 1);
    return (unsigned short)(r >> 16);
}

// ---------------------------------------------------------------------------
// Kernel 0: convert + swizzle W{g,s,v} into MFMA B-fragment order (unchanged):
//   index tau = ((m*64 + st)*4 + c)*64 + lane   (8 bf16 = 16B per entry)
// ---------------------------------------------------------------------------
__global__ __launch_bounds__(256) void convert_w(
    const float* __restrict__ Wg, const float* __restrict__ Ws,
    const float* __restrict__ Wv, unsigned short* __restrict__ Wf)
{
    int tau = blockIdx.x * 256 + threadIdx.x;      // 0..49151
    int m   = tau >> 14;
    int rem = tau & 16383;
    int st  = rem >> 8;
    int c   = (rem >> 6) & 3;
    int l   = rem & 63;
    int col = c * 16 + (l & 15);
    int k0  = st * 32 + ((l >> 4) << 3);

    const float* W = (m == 0) ? Wg : (m == 1) ? Ws : Wv;
    unsigned short out[8];
    if (col < NK) {
        const float* p = W + (size_t)col * HIDDEN + k0;
        #pragma unroll
        for (int j = 0; j < 8; j++) out[j] = f2bf(p[j]);
    } else {
        #pragma unroll
        for (int j = 0; j < 8; j++) out[j] = 0;
    }
    unsigned short* dst = Wf + (size_t)tau * 8;
    #pragma unroll
    for (int j = 0; j < 8; j++) dst[j] = out[j];
}

// ---------------------------------------------------------------------------
// Kernel 1 v10: R10's traffic-minimizing structure, compiler-managed A loads
// (the R10 NaN was un-waited asm loads; plain float4 loads restore tracked
// dependencies). BM=128, 4 waves x 32 rows (B-frag reuse x2).
// A: float4 regs -> cvt_pk bf16 -> swizzled ds_write (16KB/buf).
// B: global_load_lds DMA once per block per chunk (8KB/buf).
// Double-buffered, ONE barrier per chunk.
// Swizzle: byte_in_row ^= (row&7)<<4 on write and read (G4).
// MFMA inputs/order identical to R2..R9 (absmax 0.0156).
// ---------------------------------------------------------------------------
__global__ __launch_bounds__(256) void gemm_mfma(
    const float* __restrict__ h, const float* __restrict__ s,
    const float* __restrict__ V, const unsigned short* __restrict__ Wf,
    float* __restrict__ pg, float* __restrict__ ps, float* __restrict__ pv)
{
    int tid = threadIdx.x;
    int w = tid >> 6, lane = tid & 63;
    int blk = blockIdx.x;

    const float* A; float* C; int rowBase; const unsigned short* wfm; int Mrows;
    if (blk < 256)      { A = h; C = pg; rowBase = blk * BM;         wfm = Wf;                     Mrows = 32768; }
    else if (blk < 512) { A = s; C = ps; rowBase = (blk - 256) * BM; wfm = Wf + (size_t)16384 * 8; Mrows = 32768; }
    else                { A = V; C = pv; rowBase = (blk - 512) * BM; wfm = Wf + (size_t)32768 * 8; Mrows = 3136;  }

    __shared__ unsigned short Abf[2][BM * BK];   // 2 x 16 KB bf16, row=128B, swizzled
    __shared__ short8        Bb[2][8 * 64];      // 2 x 8 KB: frag f=st*4+c at [f*64+lane]

    const short8* wfp = (const short8*)wfm;

    // this thread's A-staging coords: row ar, fp32-col half
    int ar    = tid >> 1;          // 0..127
    int ahalf = tid & 1;           // 0,1 -> fp32 cols half*32..+31
    int agr   = rowBase + ar; if (agr > Mrows - 1) agr = Mrows - 1;
    const float* aprow = A + (size_t)agr * HIDDEN + ahalf * 32;

    f32x4 acc00 = {0.f,0.f,0.f,0.f}, acc01 = acc00, acc02 = acc00, acc03 = acc00;
    f32x4 acc10 = acc00, acc11 = acc00, acc12 = acc00, acc13 = acc00;

    float4 g0, g1, g2, g3, g4, g5, g6, g7;       // A staging regs (next chunk)

#define ALOAD(ch) { \
    const float4* _p = (const float4*)(aprow + (size_t)(ch) * BK); \
    g0 = _p[0]; g1 = _p[1]; g2 = _p[2]; g3 = _p[3]; \
    g4 = _p[4]; g5 = _p[5]; g6 = _p[6]; g7 = _p[7]; }

    // write regs (8 float4 = fp32 cols ahalf*32..+31) as bf16 into Abf[buf]
#define AWRITE(buf) { \
    char* _base = (char*)&Abf[buf][0] + ar * 128; \
    int _rk = (ar & 7) << 4; \
    uint2 v; \
    v.x = cvtpk_bf16(g0.x, g0.y); v.y = cvtpk_bf16(g0.z, g0.w); \
    *(uint2*)(_base + ((ahalf*64 + 0)  ^ _rk)) = v; \
    v.x = cvtpk_bf16(g1.x, g1.y); v.y = cvtpk_bf16(g1.z, g1.w); \
    *(uint2*)(_base + ((ahalf*64 + 8)  ^ _rk)) = v; \
    v.x = cvtpk_bf16(g2.x, g2.y); v.y = cvtpk_bf16(g2.z, g2.w); \
    *(uint2*)(_base + ((ahalf*64 + 16) ^ _rk)) = v; \
    v.x = cvtpk_bf16(g3.x, g3.y); v.y = cvtpk_bf16(g3.z, g3.w); \
    *(uint2*)(_base + ((ahalf*64 + 24) ^ _rk)) = v; \
    v.x = cvtpk_bf16(g4.x, g4.y); v.y = cvtpk_bf16(g4.z, g4.w); \
    *(uint2*)(_base + ((ahalf*64 + 32) ^ _rk)) = v; \
    v.x = cvtpk_bf16(g5.x, g5.y); v.y = cvtpk_bf16(g5.z, g5.w); \
    *(uint2*)(_base + ((ahalf*64 + 40) ^ _rk)) = v; \
    v.x = cvtpk_bf16(g6.x, g6.y); v.y = cvtpk_bf16(g6.z, g6.w); \
    *(uint2*)(_base + ((ahalf*64 + 48) ^ _rk)) = v; \
    v.x = cvtpk_bf16(g7.x, g7.y); v.y = cvtpk_bf16(g7.z, g7.w); \
    *(uint2*)(_base + ((ahalf*64 + 56) ^ _rk)) = v; }

    // B DMA for chunk ch into Bb[buf]: wave w covers frags w and w+4
#define BDMA(ch, buf) { \
    const short8* _s0 = wfp + (size_t)(((ch) * 2 + 0) * 4 + w) * 64 + lane; \
    const short8* _s1 = wfp + (size_t)(((ch) * 2 + 1) * 4 + w) * 64 + lane; \
    __builtin_amdgcn_global_load_lds((const void*)_s0, (void*)&Bb[buf][(w)     * 64], 16, 0, 0); \
    __builtin_amdgcn_global_load_lds((const void*)_s1, (void*)&Bb[buf][(w + 4) * 64], 16, 0, 0); }

    // consume chunk from buf: 2 mtiles x 2 st x 4 c MFMAs
#define COMPUTE(buf) { \
    const char*  _ab = (const char*)&Abf[buf][0]; \
    const short8* _bb = &Bb[buf][0]; \
    _Pragma("unroll") \
    for (int st = 0; st < 2; st++) { \
        int bir = st * 64 + ((lane >> 4) << 4); \
        int r0 = w * 32 + (lane & 15); \
        int r1 = r0 + 16; \
        short8 a0 = *(const short8*)(_ab + r0 * 128 + (bir ^ ((r0 & 7) << 4))); \
        short8 a1 = *(const short8*)(_ab + r1 * 128 + (bir ^ ((r1 & 7) << 4))); \
        short8 b0 = _bb[(st * 4 + 0) * 64 + lane]; \
        short8 b1 = _bb[(st * 4 + 1) * 64 + lane]; \
        short8 b2 = _bb[(st * 4 + 2) * 64 + lane]; \
        short8 b3 = _bb[(st * 4 + 3) * 64 + lane]; \
        acc00 = __builtin_amdgcn_mfma_f32_16x16x32_bf16(a0, b0, acc00, 0, 0, 0); \
        acc01 = __builtin_amdgcn_mfma_f32_16x16x32_bf16(a0, b1, acc01, 0, 0, 0); \
        acc02 = __builtin_amdgcn_mfma_f32_16x16x32_bf16(a0, b2, acc02, 0, 0, 0); \
        acc03 = __builtin_amdgcn_mfma_f32_16x16x32_bf16(a0, b3, acc03, 0, 0, 0); \
        acc10 = __builtin_amdgcn_mfma_f32_16x16x32_bf16(a1, b0, acc10, 0, 0, 0); \
        acc11 = __builtin_amdgcn_mfma_f32_16x16x32_bf16(a1, b1, acc11, 0, 0, 0); \
        acc12 = __builtin_amdgcn_mfma_f32_16x16x32_bf16(a1, b2, acc12, 0, 0, 0); \
        acc13 = __builtin_amdgcn_mfma_f32_16x16x32_bf16(a1, b3, acc13, 0, 0, 0); \
    } }

    // prologue: regs <- A(0); write buf0; BDMA(0); issue A(1); barrier
    ALOAD(0)
    AWRITE(0)
    BDMA(0, 0)
    ALOAD(1)
    __syncthreads();

    #pragma unroll 1
    for (int ch = 0; ch < NCH; ch++) {
        int p = ch & 1;
        // stage ch+1 into buf p^1 (compiler inserts the vmcnt wait on g regs)
        if (ch + 1 < NCH) {
            AWRITE(p ^ 1)
            BDMA(ch + 1, p ^ 1)
        }
        if (ch + 2 < NCH) { ALOAD(ch + 2) }   // issued ahead of compute
        COMPUTE(p)
        __syncthreads();                      // buf p free; stages for p^1 done
    }

#undef ALOAD
#undef AWRITE
#undef BDMA
#undef COMPUTE

    // C/D layout (verified m89): col = lane&15, row = (lane>>4)*4 + reg
    int colb  = lane & 15;
    int rquad = (lane >> 4) << 2;
    #pragma unroll
    for (int m = 0; m < 2; m++) {
        int rowb = rowBase + w * 32 + m * 16 + rquad;
        float* crow = C + (size_t)rowb * NK + colb;
        f32x4 a0 = m ? acc10 : acc00;
        f32x4 a1 = m ? acc11 : acc01;
        f32x4 a2 = m ? acc12 : acc02;
        f32x4 a3 = m ? acc13 : acc03;
        #pragma unroll
        for (int r = 0; r < 4; r++) {
            if (rowb + r < Mrows) {
                crow[(size_t)r * NK + 0]  = a0[r];
                crow[(size_t)r * NK + 16] = a1[r];
                crow[(size_t)r * NK + 32] = a2[r];
                if (colb == 0) crow[(size_t)r * NK + 48] = a3[r];
            }
        }
    }
}

// fast tanh: 1 - 2/(exp(2x)+1); safe at +-inf of exp
__device__ __forceinline__ float ftanh(float x) {
    float e = __expf(2.f * x);
    return 1.f - 2.f * __builtin_amdgcn_rcpf(e + 1.f);
}

// ---------------------------------------------------------------------------
// Kernel 2 v2: per-(b,t) scores + softmaxes; pv[b] staged TRANSPOSED in LDS.
// One wave per row; block = 4 rows of same b (512%4==0 -> b uniform).
// ---------------------------------------------------------------------------
__global__ __launch_bounds__(256) void zab_kernel(
    const float* __restrict__ pg, const float* __restrict__ ps,
    const float* __restrict__ pv, const float* __restrict__ Wh,
    float* __restrict__ alpha, float* __restrict__ beta)
{
    int w = threadIdx.x >> 6, lane = threadIdx.x & 63;
    int row = blockIdx.x * 4 + w;        // 0..32767
    int b = row >> 9;

    __shared__ float pvT[NK * 52];       // pvT[j*52+k] = pv[b][k][j]
    {
        const float* pvb = pv + (size_t)b * NK * NK;
        for (int i = threadIdx.x; i < NK * NK; i += 256) {
            int k = i / NK, j = i - k * NK;
            pvT[j * 52 + k] = pvb[i];
        }
    }
    __syncthreads();

    const float* pgrow = pg + (size_t)row * NK;
    const float* psrow = ps + (size_t)row * NK;

    // phase A: z_ext
    float va = 0.f;
    if (lane < NK)
        va = ftanh(psrow[lane] + pgrow[lane]) * Wh[lane];
    float z_ext = va;
    #pragma unroll
    for (int off = 32; off; off >>= 1) z_ext += __shfl_xor(z_ext, off);

    // phase B: z[k] from LDS
    float z = -1e30f;
    if (lane < NK) {
        float acc = 0.f;
        for (int j = 0; j < NK; j++)
            acc = fmaf(ftanh(pvT[j * 52 + lane] + pgrow[j]), Wh[j], acc);
        z = acc;
    }

    // softmax over k (49)
    float m = z;
    #pragma unroll
    for (int off = 32; off; off >>= 1) m = fmaxf(m, __shfl_xor(m, off));
    float p = (lane < NK) ? __expf(z - m) : 0.f;
    float ssum = p;
    #pragma unroll
    for (int off = 32; off; off >>= 1) ssum += __shfl_xor(ssum, off);
    float a = p * __builtin_amdgcn_rcpf(ssum);

    if (lane < NK)
        alpha[(size_t)row * NK + lane] = a;

    // extended softmax -> beta
    float me = fmaxf(m, z_ext);
    float se = ssum * __expf(m - me) + __expf(z_ext - me);
    float bet = __expf(z_ext - me) * __builtin_amdgcn_rcpf(se);
    if (lane == 0) beta[row] = bet;
}

// ---------------------------------------------------------------------------
// Kernel 3: c_hat = beta*sent + (1-beta)*(alpha @ V). (unchanged)
// ---------------------------------------------------------------------------
__global__ __launch_bounds__(256) void chat_kernel(
    const float* __restrict__ V, const float* __restrict__ sent,
    const float* __restrict__ alpha, const float* __restrict__ beta,
    float* __restrict__ chat)
{
    int d0 = blockIdx.x * 128;
    int t0 = blockIdx.y * 32;
    int b  = blockIdx.z;

    __shared__ float alpha_s[NK][36];   // transposed: [k][t], stride 36
    __shared__ float beta_s[32];

    int tid = threadIdx.x;

    const float* arow = alpha + ((size_t)b * NT + t0) * NK;  // 1568 contiguous
    for (int i = tid; i < 32 * NK; i += 256) {
        int t = i / NK, k = i - t * NK;
        alpha_s[k][t] = arow[i];
    }
    if (tid < 32) beta_s[tid] = beta[(size_t)b * NT + t0 + tid];
    __syncthreads();

    int tx = tid & 31;          // d-group: d = d0 + tx*4
    int ty = tid >> 5;          // t-group: t = t0 + ty*4 + i

    const float* vp = V + (size_t)b * NK * HIDDEN + d0 + tx * 4;

    float4 acc[4];
    #pragma unroll
    for (int i = 0; i < 4; i++) acc[i] = make_float4(0.f, 0.f, 0.f, 0.f);

    #pragma unroll 7
    for (int k = 0; k < NK; k++) {
        float4 vv = *(const float4*)(vp + (size_t)k * HIDDEN);
        float4 a4 = *(const float4*)&alpha_s[k][ty * 4];
        acc[0].x = fmaf(a4.x, vv.x, acc[0].x);
        acc[0].y = fmaf(a4.x, vv.y, acc[0].y);
        acc[0].z = fmaf(a4.x, vv.z, acc[0].z);
        acc[0].w = fmaf(a4.x, vv.w, acc[0].w);
        acc[1].x = fmaf(a4.y, vv.x, acc[1].x);
        acc[1].y = fmaf(a4.y, vv.y, acc[1].y);
        acc[1].z = fmaf(a4.y, vv.z, acc[1].z);
        acc[1].w = fmaf(a4.y, vv.w, acc[1].w);
        acc[2].x = fmaf(a4.z, vv.x, acc[2].x);
        acc[2].y = fmaf(a4.z, vv.y, acc[2].y);
        acc[2].z = fmaf(a4.z, vv.z, acc[2].z);
        acc[2].w = fmaf(a4.z, vv.w, acc[2].w);
        acc[3].x = fmaf(a4.w, vv.x, acc[3].x);
        acc[3].y = fmaf(a4.w, vv.y, acc[3].y);
        acc[3].z = fmaf(a4.w, vv.z, acc[3].z);
        acc[3].w = fmaf(a4.w, vv.w, acc[3].w);
    }

    #pragma unroll
    for (int i = 0; i < 4; i++) {
        int t = ty * 4 + i;
        float bt = beta_s[t];
        const float* sp = sent + ((size_t)b * NT + t0 + t) * HIDDEN + d0 + tx * 4;
        float*       op = chat + ((size_t)b * NT + t0 + t) * HIDDEN + d0 + tx * 4;
        float4 sv = *(const float4*)sp;
        float4 o;
        o.x = fmaf(bt, sv.x, (1.f - bt) * acc[i].x);
        o.y = fmaf(bt, sv.y, (1.f - bt) * acc[i].y);
        o.z = fmaf(bt, sv.z, (1.f - bt) * acc[i].z);
        o.w = fmaf(bt, sv.w, (1.f - bt) * acc[i].w);
        *(float4*)op = o;
    }
}

extern "C" void kernel_launch(void* const* d_in, const int* in_sizes, int n_in,
                              void* d_out, int out_size, void* d_ws, size_t ws_size,
                              hipStream_t stream)
{
    const float* V    = (const float*)d_in[0];
    const float* h_t  = (const float*)d_in[1];
    const float* sent = (const float*)d_in[2];
    const float* Wv   = (const float*)d_in[3];
    const float* Wg   = (const float*)d_in[4];
    const float* Ws   = (const float*)d_in[5];
    const float* Wh   = (const float*)d_in[6];

    float* out   = (float*)d_out;
    float* chat  = out;                                   // B*T*HIDDEN
    float* alpha = out + (size_t)NB * NT * HIDDEN;        // B*T*K
    float* beta  = alpha + (size_t)NB * NT * NK;          // B*T

    float* ws = (float*)d_ws;
    float* pg = ws;                                       // 32768*49
    float* ps = pg + (size_t)NB * NT * NK;                // 32768*49
    float* pv = ps + (size_t)NB * NT * NK;                // 3136*49
    unsigned short* Wf = (unsigned short*)(pv + (size_t)NB * NK * NK); // 3*16384*8 bf16

    convert_w<<<192, 256, 0, stream>>>(Wg, Ws, Wv, Wf);
    // 256 (pg) + 256 (ps) + 25 (pv, tail masked) blocks, 128 rows each
    gemm_mfma<<<537, 256, 0, stream>>>(h_t, sent, V, Wf, pg, ps, pv);
    zab_kernel<<<(NB * NT) / 4, 256, 0, stream>>>(pg, ps, pv, Wh, alpha, beta);
    chat_kernel<<<dim3(HIDDEN / 128, NT / 32, NB), 256, 0, stream>>>(V, sent, alpha, beta, chat);
}